// Round 8
// baseline (748.855 us; speedup 1.0000x reference)
//
#include <hip/hip_runtime.h>
#include <stdint.h>

// Shapes (fixed by the reference)
#define B_  4096
#define V_  5
#define D_  512
#define NN_ (B_ * V_)            // 20480 text rows
#define NBLK_ 5120               // gemm grid 32 x 160
#define NIMG4_ ((B_ * D_) / 4)   // 524288 img float4 groups

// p = exp((dot - 1)/T) = exp2(dot*C - C), C = log2(e)/T
#define C_EXP 20.609929155556620f   // 1.4426950408889634 / 0.07
#define M_SHIFT (1.0f / 0.07f)
#define SCALE1 0x7f7f7f7f           // e8m0 = 127 -> 2^0 in all 4 scale bytes

typedef float floatx4 __attribute__((ext_vector_type(4)));
typedef int   intx4   __attribute__((ext_vector_type(4)));
typedef int   intx8   __attribute__((ext_vector_type(8)));

// async global->LDS DMA, 16B per lane; LDS dest = wave-uniform base + lane*16
__device__ __forceinline__ void load_lds16(const void* g, void* l) {
  __builtin_amdgcn_global_load_lds(
      (const __attribute__((address_space(1))) unsigned int*)g,
      (__attribute__((address_space(3))) unsigned int*)l,
      16, 0, 0);
}

// agent-scope (device-coherent) load: bypasses stale per-XCD caches (G16)
__device__ __forceinline__ float aload(const float* p) {
  return __hip_atomic_load(p, __ATOMIC_RELAXED, __HIP_MEMORY_SCOPE_AGENT);
}

// ---------------------------------------------------------------------------
// SESSION RULES (R3/R4/R7 post-mortems):
//  * This kernel needs 128 regs/thread: 64 arch-VGPR + 64 AGPR (acc[4][4];
//    CSV's VGPR_Count shows only the arch half). __launch_bounds__(256,4)
//    is the ONLY valid setting: asking for 5 waves/EU caps the unified file
//    at 96 -> acc spills (R7: WRITE 609MB, gemm 200us). 4 blocks/CU is a
//    hard VGPR wall, not an LDS artifact.
//  * ANY code-motion barrier inside the superstep (s_setprio, unions,
//    sched_barrier) pins af/bf live across it -> spill (R3/R4).
//  * SQ_LDS_BANK_CONFLICT == 4 cyc per ds_read_b128 exactly (intrinsic b128
//    cost, m134) -- NOT a swizzle bug; not a target.
//  * Cross-session gemm drift ~±12% (65-74us identical code).
// R8: finish folded into gemm via last-block-done ticket (removes one
// launch + drain); cross-XCD visibility via device-scope atomics + agent
// loads per G16.
// ---------------------------------------------------------------------------
template <int CTRL>
__device__ __forceinline__ float dppadd(float v) {
  int r = __builtin_amdgcn_update_dpp(0, __builtin_bit_cast(int, v),
                                      CTRL, 0xF, 0xF, true);
  return v + __builtin_bit_cast(float, r);
}
__device__ __forceinline__ float sum16(float v) {
  v = dppadd<0x128>(v);   // row_ror:8
  v = dppadd<0x124>(v);   // row_ror:4
  v = dppadd<0x122>(v);   // row_ror:2
  v = dppadd<0x121>(v);   // row_ror:1
  return v;
}

// ---------------------------------------------------------------------------
// Kernel 1: fp32 -> fp8(e4m3) convert, fully coalesced + zeroing of the
// row/col accumulators and the last-block ticket counter.
// ---------------------------------------------------------------------------
__global__ void cvt_kernel(const float* __restrict__ img, const float* __restrict__ txt,
                           uint32_t* __restrict__ out32, float* __restrict__ acc,
                           uint32_t* __restrict__ ctr) {
  const int tid0 = blockIdx.x * 256 + threadIdx.x;   // 0..786431
  if (tid0 < B_ + NN_) acc[tid0] = 0.0f;             // zero row/col sums
  if (tid0 == 0) ctr[0] = 0u;                        // zero ticket counter
#pragma unroll
  for (int it = 0; it < 4; ++it) {
    const int idx = tid0 + it * (3072 * 256);        // float4 group index
    float4 v = (idx < NIMG4_) ? ((const float4*)img)[idx]
                              : ((const float4*)txt)[idx - NIMG4_];
    int w = __builtin_amdgcn_cvt_pk_fp8_f32(v.x, v.y, 0, 0);
    w     = __builtin_amdgcn_cvt_pk_fp8_f32(v.z, v.w, w, 1);
    out32[idx] = (uint32_t)w;
  }
}

// ---------------------------------------------------------------------------
// Kernel 2: fused MX-fp8 GEMM + exp + row/col sums + positives + (R8) the
// final loss reduction in the last-finishing block.
// Main loop byte-identical to the R2/R5 65us form.
// ---------------------------------------------------------------------------
__global__ __launch_bounds__(256, 4)
void gemm_kernel(const uint8_t* __restrict__ Ah, const uint8_t* __restrict__ Bh,
                 float* __restrict__ row_sum, float* __restrict__ col_sum,
                 float* __restrict__ posPart, float* __restrict__ out,
                 uint32_t* __restrict__ ctr) {
  __shared__ __align__(16) uint8_t As[2 * 128 * 64];   // 16 KB (2 K-tiles)
  __shared__ __align__(16) uint8_t Bs[2 * 128 * 64];   // 16 KB  (total 32768)
  const int tid  = threadIdx.x;
  const int lane = tid & 63;
  const int w    = tid >> 6;                 // wave 0..3
  const int wm   = w >> 1, wn = w & 1;       // 2x2 wave grid
  const int m0   = blockIdx.x * 128;
  const int n0   = blockIdx.y * 128;

  floatx4 acc[4][4] = {};

  // --- staging (swizzled): lane L -> row L>>2, phys chunk L&3;
  // fetches global chunk (L&3)^((L>>3)&3), i.e. LDS(r,c)=global c^((r>>1)&3).
  const int sc = ((lane & 3) ^ ((lane >> 3) & 3)) * 16;    // bytes
  const uint8_t* gA = Ah + (size_t)(m0 + w * 32 + (lane >> 2)) * D_ + sc;
  const uint8_t* gB = Bh + (size_t)(n0 + w * 32 + (lane >> 2)) * D_ + sc;
  const int lofs = (w * 32) * 64;            // wave-uniform LDS offset (bytes)

  // --- fragment addressing ---
  const int fr  = lane & 15;                 // frag m/n index
  const int swz = (fr >> 1) & 3;
  const int qb  = (lane >> 5) & 1;           // K-tile (buffer) select
  const int qh  = (lane >> 4) & 1;           // 32B half within 64B row
  const int c0  = ((qh * 2 + 0) ^ swz) * 16; // phys chunk offsets (bytes)
  const int c1  = ((qh * 2 + 1) ^ swz) * 16;
  const int bufo = qb * 8192;                // second K-tile at +8KB

  // stage K-tiles 2s, 2s+1 (tile t at global byte offset t*64)
  #define STAGE(s) do {                                            \
    const int kg = (s) * 128;                                      \
    load_lds16(gA + kg,                As + lofs);                 \
    load_lds16(gA + kg + 16 * D_,      As + lofs + 16 * 64);       \
    load_lds16(gB + kg,                Bs + lofs);                 \
    load_lds16(gB + kg + 16 * D_,      Bs + lofs + 16 * 64);       \
    load_lds16(gA + kg + 64,           As + 8192 + lofs);          \
    load_lds16(gA + kg + 64 + 16 * D_, As + 8192 + lofs + 16 * 64);\
    load_lds16(gB + kg + 64,           Bs + 8192 + lofs);          \
    load_lds16(gB + kg + 64 + 16 * D_, Bs + 8192 + lofs + 16 * 64);\
  } while (0)

  STAGE(0);                                  // prologue: fill both K-tiles

#pragma unroll
  for (int ss = 0; ss < 4; ++ss) {           // 4 supersteps x 128 K = 512
    __syncthreads();   // barrier A: drains the DMAs staged last superstep

    intx8 af[4], bf[4];
#pragma unroll
    for (int f = 0; f < 4; ++f) {
      const uint8_t* Ar = As + bufo + (wm * 64 + f * 16 + fr) * 64;
      const uint8_t* Br = Bs + bufo + (wn * 64 + f * 16 + fr) * 64;
      intx4 alo = *(const intx4*)(Ar + c0);
      intx4 ahi = *(const intx4*)(Ar + c1);
      intx4 blo = *(const intx4*)(Br + c0);
      intx4 bhi = *(const intx4*)(Br + c1);
      af[f] = __builtin_shufflevector(alo, ahi, 0, 1, 2, 3, 4, 5, 6, 7);
      bf[f] = __builtin_shufflevector(blo, bhi, 0, 1, 2, 3, 4, 5, 6, 7);
    }

    __syncthreads();   // barrier B: all reads done before in-place overwrite

    if (ss < 3) STAGE(ss + 1);               // stage next ss (overlaps MFMAs)

#pragma unroll
    for (int mf = 0; mf < 4; ++mf)
#pragma unroll
      for (int nf = 0; nf < 4; ++nf)
        acc[mf][nf] = __builtin_amdgcn_mfma_scale_f32_16x16x128_f8f6f4(
            af[mf], bf[nf], acc[mf][nf],
            0, 0,                 // cbsz=FP8(e4m3), blgp=FP8(e4m3)
            0, SCALE1,            // opsel_a, scale_a = 1.0
            0, SCALE1);           // opsel_b, scale_b = 1.0
  }
  #undef STAGE

  // --- positive extraction from RAW acc (pre-exp): row == col/5 ---
  {
    float ps = 0.0f;
    const int iLo = n0 / 5, iHi = (n0 + 127) / 5;
    if (iHi >= m0 && iLo < m0 + 128) {       // block-uniform skip (~4/5 skip)
      const int rbase = m0 + wm * 64 + ((lane >> 4) << 2);
#pragma unroll
      for (int nf = 0; nf < 4; ++nf) {
        const int ci = (n0 + wn * 64 + nf * 16 + (lane & 15)) / 5;
#pragma unroll
        for (int mf = 0; mf < 4; ++mf)
#pragma unroll
          for (int r = 0; r < 4; ++r)
            if (rbase + mf * 16 + r == ci) ps += acc[mf][nf][r];
      }
    }
    ps = sum16(ps);                          // DPP
    ps += __shfl_xor(ps, 16);
    ps += __shfl_xor(ps, 32);
    float* pls = (float*)As;                 // alias (As dead after K-loop)
    __syncthreads();                         // all waves past their last read
    if (lane == 0) pls[w] = ps;
    __syncthreads();
    if (tid == 0) {                          // agent store: visible cross-XCD
      __hip_atomic_store(&posPart[blockIdx.y * 32 + blockIdx.x],
                         pls[0] + pls[1] + pls[2] + pls[3],
                         __ATOMIC_RELAXED, __HIP_MEMORY_SCOPE_AGENT);
    }
  }

  // Epilogue: p = exp2(dot*C - C); C/D layout: col=lane&15, row=(lane>>4)*4+reg
#pragma unroll
  for (int mf = 0; mf < 4; ++mf)
#pragma unroll
    for (int nf = 0; nf < 4; ++nf)
#pragma unroll
      for (int r = 0; r < 4; ++r)
        acc[mf][nf][r] = exp2f(acc[mf][nf][r] * C_EXP - C_EXP);

  // column sums over this wave's 64 rows (cross-row: keep shfl)
  float cs[4];
#pragma unroll
  for (int nf = 0; nf < 4; ++nf) {
    float s = 0.0f;
#pragma unroll
    for (int mf = 0; mf < 4; ++mf)
      s += acc[mf][nf][0] + acc[mf][nf][1] + acc[mf][nf][2] + acc[mf][nf][3];
    s += __shfl_xor(s, 16);
    s += __shfl_xor(s, 32);
    cs[nf] = s;
  }
  {
    int g = lane >> 4;                        // lane group g holds frag g's sums
    float v = (g == 0) ? cs[0] : (g == 1) ? cs[1] : (g == 2) ? cs[2] : cs[3];
    atomicAdd(&col_sum[n0 + wn * 64 + (g << 4) + (lane & 15)], v);
  }

  // row sums over this wave's 64 cols -- DPP reduce
#pragma unroll
  for (int mf = 0; mf < 4; ++mf) {
    floatx4 t = acc[mf][0] + acc[mf][1] + acc[mf][2] + acc[mf][3];
#pragma unroll
    for (int r = 0; r < 4; ++r) t[r] = sum16(t[r]);
    if ((lane & 15) < 4) {                    // 16 lanes cover 16 rows of this m-frag
      int q = lane & 3;
      float v = (q == 0) ? t[0] : (q == 1) ? t[1] : (q == 2) ? t[2] : t[3];
      atomicAdd(&row_sum[m0 + wm * 64 + mf * 16 + ((lane >> 4) << 2) + q], v);
    }
  }

  // --- R8: last-block-done fused finish -----------------------------------
  // Each block: fence its atomics, then take a ticket (acq_rel). The block
  // drawing ticket NBLK-1 knows all 5120 blocks' atomics are visible and
  // runs the final reduction with its 256 threads (agent-scope loads
  // bypass stale per-XCD caches).
  __threadfence();
  __syncthreads();
  uint32_t* flag = (uint32_t*)Bs;            // Bs dead after K-loop
  if (tid == 0) {
    uint32_t t = __hip_atomic_fetch_add(ctr, 1u, __ATOMIC_ACQ_REL,
                                        __HIP_MEMORY_SCOPE_AGENT);
    flag[0] = (t == (uint32_t)(NBLK_ - 1)) ? 1u : 0u;
  }
  __syncthreads();
  if (flag[0] != 0u) {                       // block-uniform branch
    float sA = 0.0f, sB = 0.0f, sP = 0.0f;
    for (int i = tid; i < B_;    i += 256) sA += logf(aload(&row_sum[i]));
    for (int i = tid; i < NN_;   i += 256) sB += logf(aload(&col_sum[i]));
    for (int i = tid; i < NBLK_; i += 256) sP += aload(&posPart[i]);
    float s = sA * (1.0f / B_) + sB * (1.0f / NN_)
            - sP * (2.0f * M_SHIFT / (float)NN_);
    s = sum16(s);
    s += __shfl_xor(s, 16);
    s += __shfl_xor(s, 32);
    float* ls = (float*)Bs + 4;              // past the flag word
    if (lane == 0) ls[w] = s;
    __syncthreads();
    if (tid == 0)
      out[0] = M_SHIFT + 0.5f * (ls[0] + ls[1] + ls[2] + ls[3]);
  }
}

// ---------------------------------------------------------------------------
extern "C" void kernel_launch(void* const* d_in, const int* in_sizes, int n_in,
                              void* d_out, int out_size, void* d_ws, size_t ws_size,
                              hipStream_t stream) {
  const float* img = (const float*)d_in[0];   // (4096, 512) fp32
  const float* txt = (const float*)d_in[1];   // (4096, 5, 512) fp32

  // workspace: [ img_fp8 | txt_fp8 | row_sum(B) col_sum(NN) posPart(NBLK) ctr ]
  const size_t fp8Bytes = (size_t)(B_ * D_ + NN_ * D_);           // 12,582,912
  const size_t needBytes = fp8Bytes + (size_t)(B_ + NN_ + NBLK_ + 1) * 4;
  if (ws_size < needBytes) return;            // fail loudly (absmax), don't fault

  uint8_t* Ah  = (uint8_t*)d_ws;              // B*D bytes (txt follows contiguously)
  uint8_t* Bh  = Ah + (size_t)B_ * D_;        // NN*D bytes
  float* acc   = (float*)((char*)d_ws + fp8Bytes);
  float* row_s = acc;                         // [0, B_)
  float* col_s = acc + B_;                    // [B_, B_+NN_)
  float* posP  = acc + B_ + NN_;              // [B_+NN_, +NBLK_)
  uint32_t* ctr = (uint32_t*)(posP + NBLK_);  // 1 word

  cvt_kernel <<<3072, 256, 0, stream>>>(img, txt, (uint32_t*)Ah, acc, ctr);
  gemm_kernel<<<dim3(32, 160), 256, 0, stream>>>(Ah, Bh, row_s, col_s, posP,
                                                 (float*)d_out, ctr);
}

// Round 9
// 142.692 us; speedup vs baseline: 5.2480x; 5.2480x over previous
//
#include <hip/hip_runtime.h>
#include <stdint.h>

// Shapes (fixed by the reference)
#define B_  4096
#define V_  5
#define D_  512
#define NN_ (B_ * V_)            // 20480 text rows
#define NBLK_ 5120               // gemm grid 32 x 160
#define NIMG4_ ((B_ * D_) / 4)   // 524288 img float4 groups

// p = exp((dot - 1)/T) = exp2(dot*C - C), C = log2(e)/T
#define C_EXP 20.609929155556620f   // 1.4426950408889634 / 0.07
#define M_SHIFT (1.0f / 0.07f)
#define SCALE1 0x7f7f7f7f           // e8m0 = 127 -> 2^0 in all 4 scale bytes

#define FIN_BLOCKS 16               // finish kernel grid

typedef float floatx4 __attribute__((ext_vector_type(4)));
typedef int   intx4   __attribute__((ext_vector_type(4)));
typedef int   intx8   __attribute__((ext_vector_type(8)));

// async global->LDS DMA, 16B per lane; LDS dest = wave-uniform base + lane*16
__device__ __forceinline__ void load_lds16(const void* g, void* l) {
  __builtin_amdgcn_global_load_lds(
      (const __attribute__((address_space(1))) unsigned int*)g,
      (__attribute__((address_space(3))) unsigned int*)l,
      16, 0, 0);
}

// ---------------------------------------------------------------------------
// SESSION RULES (R3/R4/R7/R8 post-mortems):
//  * 128 regs/thread needed: 64 arch-VGPR + 64 AGPR (acc[4][4]; CSV shows
//    only the arch half). __launch_bounds__(256,4) is the ONLY valid
//    setting; (256,5) caps the unified file at 96 -> acc spills (R7:
//    WRITE 609MB, 200us). 4 blocks/CU is a hard VGPR wall.
//  * ANY code-motion barrier inside the superstep (s_setprio, unions,
//    sched_barrier) pins af/bf live across it -> spill (R3/R4).
//  * __threadfence()/acq_rel atomics on the per-block path emit L2
//    writeback/invalidate -> chip-wide serialization, +580us over 5120
//    blocks (R8). Final reduction stays a separate kernel.
//  * SQ_LDS_BANK_CONFLICT == 4 cyc per ds_read_b128 exactly (intrinsic
//    b128 cost, m134) -- not a target.
//  * Cross-session gemm drift ~±12% (65-74us identical code); FETCH_SIZE
//    is the noise-free mechanism signal.
// R9: T1 XCD-chunked tile swizzle. Consecutive hw block ids round-robin
// XCDs; remap so XCD k owns tiles [k*640,(k+1)*640) m-fastest -> per-XCD
// L2 working set = all of A (2MB, reused 20x) + streamed B panels < 4MB.
// Mechanism: shorter DMA completions (L2 vs HBM latency) at barrier A.
// ---------------------------------------------------------------------------
template <int CTRL>
__device__ __forceinline__ float dppadd(float v) {
  int r = __builtin_amdgcn_update_dpp(0, __builtin_bit_cast(int, v),
                                      CTRL, 0xF, 0xF, true);
  return v + __builtin_bit_cast(float, r);
}
__device__ __forceinline__ float sum16(float v) {
  v = dppadd<0x128>(v);   // row_ror:8
  v = dppadd<0x124>(v);   // row_ror:4
  v = dppadd<0x122>(v);   // row_ror:2
  v = dppadd<0x121>(v);   // row_ror:1
  return v;
}

// ---------------------------------------------------------------------------
// Kernel 1: fp32 -> fp8(e4m3) convert, fully coalesced + accumulator zeroing.
// Seeds out[0] = M_SHIFT (stream-ordered before finish's atomicAdd).
// ---------------------------------------------------------------------------
__global__ void cvt_kernel(const float* __restrict__ img, const float* __restrict__ txt,
                           uint32_t* __restrict__ out32, float* __restrict__ acc,
                           float* __restrict__ out) {
  const int tid0 = blockIdx.x * 256 + threadIdx.x;   // 0..786431
  if (tid0 < B_ + NN_) acc[tid0] = 0.0f;             // zero row/col sums
  if (tid0 == 0) out[0] = M_SHIFT;                   // seed final accumulator
#pragma unroll
  for (int it = 0; it < 4; ++it) {
    const int idx = tid0 + it * (3072 * 256);        // float4 group index
    float4 v = (idx < NIMG4_) ? ((const float4*)img)[idx]
                              : ((const float4*)txt)[idx - NIMG4_];
    int w = __builtin_amdgcn_cvt_pk_fp8_f32(v.x, v.y, 0, 0);
    w     = __builtin_amdgcn_cvt_pk_fp8_f32(v.z, v.w, w, 1);
    out32[idx] = (uint32_t)w;
  }
}

// ---------------------------------------------------------------------------
// Kernel 2: fused MX-fp8 GEMM + exp + row/col sums + positives.
// Main loop identical to the R2/R5 65us form; R9 adds only the tile swizzle.
// ---------------------------------------------------------------------------
__global__ __launch_bounds__(256, 4)
void gemm_kernel(const uint8_t* __restrict__ Ah, const uint8_t* __restrict__ Bh,
                 float* __restrict__ row_sum, float* __restrict__ col_sum,
                 float* __restrict__ posPart) {
  __shared__ __align__(16) uint8_t As[2 * 128 * 64];   // 16 KB (2 K-tiles)
  __shared__ __align__(16) uint8_t Bs[2 * 128 * 64];   // 16 KB
  const int tid  = threadIdx.x;
  const int lane = tid & 63;
  const int w    = tid >> 6;                 // wave 0..3
  const int wm   = w >> 1, wn = w & 1;       // 2x2 wave grid

  // --- R9: XCD-chunked swizzle (bijective: 5120 % 8 == 0) ---
  const int lin = blockIdx.y * 32 + blockIdx.x;       // hw dispatch order
  const int swz = (lin & 7) * (NBLK_ / 8) + (lin >> 3);
  const int m0  = (swz & 31) * 128;                   // m-fastest in chunk
  const int n0  = (swz >> 5) * 128;

  floatx4 acc[4][4] = {};

  // --- staging (swizzled): lane L -> row L>>2, phys chunk L&3;
  // fetches global chunk (L&3)^((L>>3)&3), i.e. LDS(r,c)=global c^((r>>1)&3).
  const int sc = ((lane & 3) ^ ((lane >> 3) & 3)) * 16;    // bytes
  const uint8_t* gA = Ah + (size_t)(m0 + w * 32 + (lane >> 2)) * D_ + sc;
  const uint8_t* gB = Bh + (size_t)(n0 + w * 32 + (lane >> 2)) * D_ + sc;
  const int lofs = (w * 32) * 64;            // wave-uniform LDS offset (bytes)

  // --- fragment addressing ---
  const int fr  = lane & 15;                 // frag m/n index
  const int fswz = (fr >> 1) & 3;
  const int qb  = (lane >> 5) & 1;           // K-tile (buffer) select
  const int qh  = (lane >> 4) & 1;           // 32B half within 64B row
  const int c0  = ((qh * 2 + 0) ^ fswz) * 16; // phys chunk offsets (bytes)
  const int c1  = ((qh * 2 + 1) ^ fswz) * 16;
  const int bufo = qb * 8192;                // second K-tile at +8KB

  // stage K-tiles 2s, 2s+1 (tile t at global byte offset t*64)
  #define STAGE(s) do {                                            \
    const int kg = (s) * 128;                                      \
    load_lds16(gA + kg,                As + lofs);                 \
    load_lds16(gA + kg + 16 * D_,      As + lofs + 16 * 64);       \
    load_lds16(gB + kg,                Bs + lofs);                 \
    load_lds16(gB + kg + 16 * D_,      Bs + lofs + 16 * 64);       \
    load_lds16(gA + kg + 64,           As + 8192 + lofs);          \
    load_lds16(gA + kg + 64 + 16 * D_, As + 8192 + lofs + 16 * 64);\
    load_lds16(gB + kg + 64,           Bs + 8192 + lofs);          \
    load_lds16(gB + kg + 64 + 16 * D_, Bs + 8192 + lofs + 16 * 64);\
  } while (0)

  STAGE(0);                                  // prologue: fill both K-tiles

#pragma unroll
  for (int ss = 0; ss < 4; ++ss) {           // 4 supersteps x 128 K = 512
    __syncthreads();   // barrier A: drains the DMAs staged last superstep

    intx8 af[4], bf[4];
#pragma unroll
    for (int f = 0; f < 4; ++f) {
      const uint8_t* Ar = As + bufo + (wm * 64 + f * 16 + fr) * 64;
      const uint8_t* Br = Bs + bufo + (wn * 64 + f * 16 + fr) * 64;
      intx4 alo = *(const intx4*)(Ar + c0);
      intx4 ahi = *(const intx4*)(Ar + c1);
      intx4 blo = *(const intx4*)(Br + c0);
      intx4 bhi = *(const intx4*)(Br + c1);
      af[f] = __builtin_shufflevector(alo, ahi, 0, 1, 2, 3, 4, 5, 6, 7);
      bf[f] = __builtin_shufflevector(blo, bhi, 0, 1, 2, 3, 4, 5, 6, 7);
    }

    __syncthreads();   // barrier B: all reads done before in-place overwrite

    if (ss < 3) STAGE(ss + 1);               // stage next ss (overlaps MFMAs)

#pragma unroll
    for (int mf = 0; mf < 4; ++mf)
#pragma unroll
      for (int nf = 0; nf < 4; ++nf)
        acc[mf][nf] = __builtin_amdgcn_mfma_scale_f32_16x16x128_f8f6f4(
            af[mf], bf[nf], acc[mf][nf],
            0, 0,                 // cbsz=FP8(e4m3), blgp=FP8(e4m3)
            0, SCALE1,            // opsel_a, scale_a = 1.0
            0, SCALE1);           // opsel_b, scale_b = 1.0
  }
  #undef STAGE

  // --- positive extraction from RAW acc (pre-exp): row == col/5 ---
  {
    float ps = 0.0f;
    const int iLo = n0 / 5, iHi = (n0 + 127) / 5;
    if (iHi >= m0 && iLo < m0 + 128) {       // block-uniform skip (~4/5 skip)
      const int rbase = m0 + wm * 64 + ((lane >> 4) << 2);
#pragma unroll
      for (int nf = 0; nf < 4; ++nf) {
        const int ci = (n0 + wn * 64 + nf * 16 + (lane & 15)) / 5;
#pragma unroll
        for (int mf = 0; mf < 4; ++mf)
#pragma unroll
          for (int r = 0; r < 4; ++r)
            if (rbase + mf * 16 + r == ci) ps += acc[mf][nf][r];
      }
    }
    ps = sum16(ps);                          // DPP
    ps += __shfl_xor(ps, 16);
    ps += __shfl_xor(ps, 32);
    __shared__ float pls[4];
    if (lane == 0) pls[w] = ps;
    __syncthreads();
    if (tid == 0)
      posPart[swz] = pls[0] + pls[1] + pls[2] + pls[3];   // bijective index
  }

  // Epilogue: p = exp2(dot*C - C); C/D layout: col=lane&15, row=(lane>>4)*4+reg
#pragma unroll
  for (int mf = 0; mf < 4; ++mf)
#pragma unroll
    for (int nf = 0; nf < 4; ++nf)
#pragma unroll
      for (int r = 0; r < 4; ++r)
        acc[mf][nf][r] = exp2f(acc[mf][nf][r] * C_EXP - C_EXP);

  // column sums over this wave's 64 rows (cross-row: keep shfl)
  float cs[4];
#pragma unroll
  for (int nf = 0; nf < 4; ++nf) {
    float s = 0.0f;
#pragma unroll
    for (int mf = 0; mf < 4; ++mf)
      s += acc[mf][nf][0] + acc[mf][nf][1] + acc[mf][nf][2] + acc[mf][nf][3];
    s += __shfl_xor(s, 16);
    s += __shfl_xor(s, 32);
    cs[nf] = s;
  }
  {
    int g = lane >> 4;                        // lane group g holds frag g's sums
    float v = (g == 0) ? cs[0] : (g == 1) ? cs[1] : (g == 2) ? cs[2] : cs[3];
    atomicAdd(&col_sum[n0 + wn * 64 + (g << 4) + (lane & 15)], v);
  }

  // row sums over this wave's 64 cols -- DPP reduce
#pragma unroll
  for (int mf = 0; mf < 4; ++mf) {
    floatx4 t = acc[mf][0] + acc[mf][1] + acc[mf][2] + acc[mf][3];
#pragma unroll
    for (int r = 0; r < 4; ++r) t[r] = sum16(t[r]);
    if ((lane & 15) < 4) {                    // 16 lanes cover 16 rows of this m-frag
      int q = lane & 3;
      float v = (q == 0) ? t[0] : (q == 1) ? t[1] : (q == 2) ? t[2] : t[3];
      atomicAdd(&row_sum[m0 + wm * 64 + mf * 16 + ((lane >> 4) << 2) + q], v);
    }
  }
}

// ---------------------------------------------------------------------------
// Kernel 3 (multi-block): out[0] (= M_SHIFT, seeded by cvt) +=
// 0.5 * (mean log rowsum + mean log colsum - 2*pos/(BV)) per-block atomicAdd.
// ---------------------------------------------------------------------------
__global__ void finish_kernel(const float* __restrict__ acc, const float* __restrict__ posPart,
                              float* __restrict__ out) {
  const int tid = blockIdx.x * 1024 + threadIdx.x;   // FIN_BLOCKS x 1024
  const int stride = FIN_BLOCKS * 1024;
  float sA = 0.0f, sB = 0.0f, sP = 0.0f;
  for (int i = tid; i < B_;    i += stride) sA += logf(acc[i]);
  for (int i = tid; i < NN_;   i += stride) sB += logf(acc[B_ + i]);
  for (int i = tid; i < NBLK_; i += stride) sP += posPart[i];
  float s = sA * (1.0f / B_) + sB * (1.0f / NN_)
          - sP * (2.0f * M_SHIFT / (float)NN_);
  for (int o = 32; o; o >>= 1) s += __shfl_xor(s, o);
  __shared__ float ls[16];
  int lane = threadIdx.x & 63, w = threadIdx.x >> 6;
  if (lane == 0) ls[w] = s;
  __syncthreads();
  if (threadIdx.x == 0) {
    float tot = 0.0f;
#pragma unroll
    for (int i = 0; i < 16; ++i) tot += ls[i];
    atomicAdd(out, 0.5f * tot);
  }
}

// ---------------------------------------------------------------------------
extern "C" void kernel_launch(void* const* d_in, const int* in_sizes, int n_in,
                              void* d_out, int out_size, void* d_ws, size_t ws_size,
                              hipStream_t stream) {
  const float* img = (const float*)d_in[0];   // (4096, 512) fp32
  const float* txt = (const float*)d_in[1];   // (4096, 5, 512) fp32

  // workspace: [ img_fp8 | txt_fp8 | row_sum(B) col_sum(NN) posPart(NBLK) ]
  const size_t fp8Bytes = (size_t)(B_ * D_ + NN_ * D_);           // 12,582,912
  const size_t needBytes = fp8Bytes + (size_t)(B_ + NN_ + NBLK_) * 4;
  if (ws_size < needBytes) return;            // fail loudly (absmax), don't fault

  uint8_t* Ah  = (uint8_t*)d_ws;              // B*D bytes (txt follows contiguously)
  uint8_t* Bh  = Ah + (size_t)B_ * D_;        // NN*D bytes
  float* acc   = (float*)((char*)d_ws + fp8Bytes);
  float* row_s = acc;                         // [0, B_)
  float* col_s = acc + B_;                    // [B_, B_+NN_)
  float* posP  = acc + B_ + NN_;              // [B_+NN_, +NBLK_)

  cvt_kernel   <<<3072, 256, 0, stream>>>(img, txt, (uint32_t*)Ah, acc, (float*)d_out);
  gemm_kernel  <<<dim3(32, 160), 256, 0, stream>>>(Ah, Bh, row_s, col_s, posP);
  finish_kernel<<<FIN_BLOCKS, 1024, 0, stream>>>(acc, posP, (float*)d_out);
}